// Round 1
// baseline (653.975 us; speedup 1.0000x reference)
//
#include <hip/hip_runtime.h>

#define DCOL 256

__global__ void copy_f4(const float4* __restrict__ src, float4* __restrict__ dst, int n4) {
    int i = blockIdx.x * blockDim.x + threadIdx.x;
    int stride = gridDim.x * blockDim.x;
    for (; i < n4; i += stride) dst[i] = src[i];
}

__global__ void scatter_add4(const int4* __restrict__ index,
                             const float4* __restrict__ upd,
                             float* __restrict__ out, int n4) {
    int i = blockIdx.x * blockDim.x + threadIdx.x;
    int stride = gridDim.x * blockDim.x;
    for (; i < n4; i += stride) {
        int4 idx  = index[i];
        float4 u  = upd[i];
        int j = (i << 2) & (DCOL - 1);  // column of first of the 4 elements
        atomicAdd(&out[idx.x * DCOL + j + 0], u.x);
        atomicAdd(&out[idx.y * DCOL + j + 1], u.y);
        atomicAdd(&out[idx.z * DCOL + j + 2], u.z);
        atomicAdd(&out[idx.w * DCOL + j + 3], u.w);
    }
}

extern "C" void kernel_launch(void* const* d_in, const int* in_sizes, int n_in,
                              void* d_out, int out_size, void* d_ws, size_t ws_size,
                              hipStream_t stream) {
    const float* self_t = (const float*)d_in[0];   // N*D fp32
    const int*   index  = (const int*)d_in[1];     // M*D int32
    const float* upd    = (const float*)d_in[2];   // M*D fp32
    float* out = (float*)d_out;

    const int nd = out_size;          // N*D = 25,600,000
    const int md = in_sizes[1];       // M*D = 12,800,000

    // 1) out = self_tensor (must run every call: harness poisons d_out once
    //    and never restores it between timed replays)
    {
        int n4 = nd / 4;
        int block = 256, grid = 2048;
        copy_f4<<<grid, block, 0, stream>>>((const float4*)self_t, (float4*)out, n4);
    }

    // 2) out[index[i,j], j] += updates[i,j]
    {
        int n4 = md / 4;
        int block = 256, grid = 4096;
        scatter_add4<<<grid, block, 0, stream>>>((const int4*)index,
                                                 (const float4*)upd, out, n4);
    }
}

// Round 2
// 309.449 us; speedup vs baseline: 2.1134x; 2.1134x over previous
//
#include <hip/hip_runtime.h>

#define DCOLS 256
#define RB 128            // rows per bin -> LDS slice = 128*256*4 = 128 KB
#define MAXBINS 800       // ceil(100000/128)=782, padded
#define PAIRS_OFF 16384   // byte offset of pairs[] in d_ws

typedef unsigned int u32;
typedef unsigned long long u64;

// ---------------- fallback path (round-1 kernels) ----------------
__global__ void copy_f4(const float4* __restrict__ src, float4* __restrict__ dst, int n4) {
    int i = blockIdx.x * blockDim.x + threadIdx.x;
    int stride = gridDim.x * blockDim.x;
    for (; i < n4; i += stride) dst[i] = src[i];
}

__global__ void scatter_add4(const int4* __restrict__ index,
                             const float4* __restrict__ upd,
                             float* __restrict__ out, int n4) {
    int i = blockIdx.x * blockDim.x + threadIdx.x;
    int stride = gridDim.x * blockDim.x;
    for (; i < n4; i += stride) {
        int4 idx  = index[i];
        float4 u  = upd[i];
        int j = (i << 2) & (DCOLS - 1);
        atomicAdd(&out[idx.x * DCOLS + j + 0], u.x);
        atomicAdd(&out[idx.y * DCOLS + j + 1], u.y);
        atomicAdd(&out[idx.z * DCOLS + j + 2], u.z);
        atomicAdd(&out[idx.w * DCOLS + j + 3], u.w);
    }
}

// ---------------- binned path ----------------
__global__ void zero_meta(u32* __restrict__ count, int nbins) {
    int i = threadIdx.x;
    if (i < nbins) count[i] = 0;
}

__global__ void __launch_bounds__(256) count_bins(const int4* __restrict__ idx4,
                                                  u32* __restrict__ count, int n4) {
    __shared__ u32 hist[MAXBINS];
    for (int i = threadIdx.x; i < MAXBINS; i += blockDim.x) hist[i] = 0;
    __syncthreads();
    int i = blockIdx.x * blockDim.x + threadIdx.x;
    int stride = gridDim.x * blockDim.x;
    for (; i < n4; i += stride) {
        int4 v = idx4[i];
        atomicAdd(&hist[((u32)v.x) >> 7], 1u);
        atomicAdd(&hist[((u32)v.y) >> 7], 1u);
        atomicAdd(&hist[((u32)v.z) >> 7], 1u);
        atomicAdd(&hist[((u32)v.w) >> 7], 1u);
    }
    __syncthreads();
    for (int i2 = threadIdx.x; i2 < MAXBINS; i2 += blockDim.x)
        if (hist[i2]) atomicAdd(&count[i2], hist[i2]);
}

__global__ void scan_bins(const u32* __restrict__ count, u32* __restrict__ start,
                          u32* __restrict__ cursor, int nbins) {
    __shared__ u32 tmp[1024];
    int t = threadIdx.x;
    u32 v = (t < nbins) ? count[t] : 0u;
    tmp[t] = v;
    __syncthreads();
    for (int off = 1; off < 1024; off <<= 1) {
        u32 a = 0;
        if (t >= off) a = tmp[t - off];
        __syncthreads();
        tmp[t] += a;
        __syncthreads();
    }
    if (t < nbins) {
        u32 excl = tmp[t] - v;   // exclusive prefix
        start[t] = excl;
        cursor[t] = excl;
    }
}

// one block handles 1024 int4 = 4096 elements
__global__ void __launch_bounds__(256) bin_scatter(const int4* __restrict__ idx4,
                                                   const float4* __restrict__ upd4,
                                                   u32* __restrict__ cursor,
                                                   u64* __restrict__ pairs, int n4) {
    __shared__ u32 hist[MAXBINS];
    __shared__ u32 basep[MAXBINS];
    int t = threadIdx.x;
    int b4 = blockIdx.x * 1024;
    for (int i = t; i < MAXBINS; i += 256) hist[i] = 0;
    __syncthreads();

    int4 iv[4]; float4 uv[4]; bool valid[4];
#pragma unroll
    for (int k = 0; k < 4; ++k) {
        int p = b4 + t + 256 * k;
        valid[k] = p < n4;
        if (valid[k]) { iv[k] = idx4[p]; uv[k] = upd4[p]; }
    }
#pragma unroll
    for (int k = 0; k < 4; ++k) {
        if (valid[k]) {
            atomicAdd(&hist[((u32)iv[k].x) >> 7], 1u);
            atomicAdd(&hist[((u32)iv[k].y) >> 7], 1u);
            atomicAdd(&hist[((u32)iv[k].z) >> 7], 1u);
            atomicAdd(&hist[((u32)iv[k].w) >> 7], 1u);
        }
    }
    __syncthreads();
    for (int p = t; p < MAXBINS; p += 256) {
        u32 c = hist[p];
        basep[p] = c ? atomicAdd(&cursor[p], c) : 0u;
    }
    __syncthreads();
    for (int p = t; p < MAXBINS; p += 256) hist[p] = 0;
    __syncthreads();

    u32 colbase = ((u32)t * 4u) & 255u;   // element e = (b4+t+256k)*4+c -> e%256 = (4t+c)%256
#pragma unroll
    for (int k = 0; k < 4; ++k) {
        if (!valid[k]) continue;
        int rows[4] = {iv[k].x, iv[k].y, iv[k].z, iv[k].w};
        float vals[4] = {uv[k].x, uv[k].y, uv[k].z, uv[k].w};
#pragma unroll
        for (int c = 0; c < 4; ++c) {
            u32 row = (u32)rows[c];
            u32 bin = row >> 7;
            u32 off = atomicAdd(&hist[bin], 1u);
            u32 key = ((row & 127u) << 8) | ((colbase + (u32)c) & 255u);
            pairs[basep[bin] + off] = ((u64)__float_as_uint(vals[c]) << 32) | (u64)key;
        }
    }
}

// one block per bin: LDS-accumulate pairs, then out = self + acc (fused copy)
__global__ void __launch_bounds__(512) apply_bins(const float4* __restrict__ self4,
                                                  const u64* __restrict__ pairs,
                                                  const u32* __restrict__ start,
                                                  const u32* __restrict__ endc,
                                                  float4* __restrict__ out4, int nrows) {
    __shared__ float acc[RB * DCOLS];   // 128 KB
    int t = threadIdx.x;
    int b = blockIdx.x;
    float4* acc4 = (float4*)acc;
    const int NACC4 = RB * DCOLS / 4;   // 8192
    for (int i = t; i < NACC4; i += 512) acc4[i] = make_float4(0.f, 0.f, 0.f, 0.f);
    __syncthreads();

    u32 s = start[b], e = endc[b];
    for (u32 i = s + (u32)t; i < e; i += 512u) {
        u64 pr = pairs[i];
        u32 key = (u32)pr & 0x7fffu;
        atomicAdd(&acc[key], __uint_as_float((u32)(pr >> 32)));
    }
    __syncthreads();

    int r0 = b * RB;
    int nr = nrows - r0; if (nr > RB) nr = RB;
    int tot4 = nr * (DCOLS / 4);
    long base4 = (long)r0 * (DCOLS / 4);
    for (int i = t; i < tot4; i += 512) {
        float4 a = self4[base4 + i];
        float4 c = acc4[i];
        a.x += c.x; a.y += c.y; a.z += c.z; a.w += c.w;
        out4[base4 + i] = a;
    }
}

extern "C" void kernel_launch(void* const* d_in, const int* in_sizes, int n_in,
                              void* d_out, int out_size, void* d_ws, size_t ws_size,
                              hipStream_t stream) {
    const float* self_t = (const float*)d_in[0];   // N*D fp32
    const int*   index  = (const int*)d_in[1];     // M*D int32
    const float* upd    = (const float*)d_in[2];   // M*D fp32
    float* out = (float*)d_out;

    const int nd = out_size;      // N*D
    const int md = in_sizes[1];   // M*D
    const int nrows = nd / DCOLS;
    const int nbins = (nrows + RB - 1) / RB;

    size_t need = (size_t)PAIRS_OFF + (size_t)md * 8;
    if (ws_size < need || nbins > MAXBINS || (md & 3) || (nd & 3)) {
        // workspace too small or unexpected shape: direct-atomic fallback
        copy_f4<<<2048, 256, 0, stream>>>((const float4*)self_t, (float4*)out, nd / 4);
        scatter_add4<<<4096, 256, 0, stream>>>((const int4*)index, (const float4*)upd, out, md / 4);
        return;
    }

    u32* count  = (u32*)d_ws;          // 800 u32 (padded region)
    u32* start  = count + 1024;
    u32* cursor = count + 2048;
    u64* pairs  = (u64*)((char*)d_ws + PAIRS_OFF);
    int n4 = md / 4;

    zero_meta<<<1, 1024, 0, stream>>>(count, nbins);
    count_bins<<<1024, 256, 0, stream>>>((const int4*)index, count, n4);
    scan_bins<<<1, 1024, 0, stream>>>(count, start, cursor, nbins);
    int sblocks = (n4 + 1023) / 1024;
    bin_scatter<<<sblocks, 256, 0, stream>>>((const int4*)index, (const float4*)upd,
                                             cursor, pairs, n4);
    apply_bins<<<nbins, 512, 0, stream>>>((const float4*)self_t, pairs, start, cursor,
                                          (float4*)out, nrows);
}

// Round 3
// 255.281 us; speedup vs baseline: 2.5618x; 1.2122x over previous
//
#include <hip/hip_runtime.h>

#define DCOLS 256
#define RB 128            // rows per bin -> LDS slice = 128*256*4 = 128 KB
#define MAXBINS 800       // ceil(100000/128)=782, padded
#define NBIN_PAD 1024
#define PAIRS_OFF 16384   // byte offset of pairs[] in d_ws
#define CHUNK4 4096       // int4 per block in bin_scatter_v2 (16384 elements)
#define SUB4 1024         // int4 per sub-chunk (4096 elements)
#define NSUB (CHUNK4 / SUB4)

typedef unsigned int u32;
typedef unsigned long long u64;

// ---------------- fallback path ----------------
__global__ void copy_f4(const float4* __restrict__ src, float4* __restrict__ dst, int n4) {
    int i = blockIdx.x * blockDim.x + threadIdx.x;
    int stride = gridDim.x * blockDim.x;
    for (; i < n4; i += stride) dst[i] = src[i];
}

__global__ void scatter_add4(const int4* __restrict__ index,
                             const float4* __restrict__ upd,
                             float* __restrict__ out, int n4) {
    int i = blockIdx.x * blockDim.x + threadIdx.x;
    int stride = gridDim.x * blockDim.x;
    for (; i < n4; i += stride) {
        int4 idx  = index[i];
        float4 u  = upd[i];
        int j = (i << 2) & (DCOLS - 1);
        atomicAdd(&out[idx.x * DCOLS + j + 0], u.x);
        atomicAdd(&out[idx.y * DCOLS + j + 1], u.y);
        atomicAdd(&out[idx.z * DCOLS + j + 2], u.z);
        atomicAdd(&out[idx.w * DCOLS + j + 3], u.w);
    }
}

// ---------------- binned path ----------------
__global__ void zero_meta(u32* __restrict__ count, int nbins) {
    int i = threadIdx.x;
    if (i < nbins) count[i] = 0;
}

__global__ void __launch_bounds__(256) count_bins(const int4* __restrict__ idx4,
                                                  u32* __restrict__ count, int n4) {
    __shared__ u32 hist[NBIN_PAD];
    for (int i = threadIdx.x; i < NBIN_PAD; i += blockDim.x) hist[i] = 0;
    __syncthreads();
    int i = blockIdx.x * blockDim.x + threadIdx.x;
    int stride = gridDim.x * blockDim.x;
    for (; i < n4; i += stride) {
        int4 v = idx4[i];
        atomicAdd(&hist[((u32)v.x) >> 7], 1u);
        atomicAdd(&hist[((u32)v.y) >> 7], 1u);
        atomicAdd(&hist[((u32)v.z) >> 7], 1u);
        atomicAdd(&hist[((u32)v.w) >> 7], 1u);
    }
    __syncthreads();
    for (int i2 = threadIdx.x; i2 < NBIN_PAD; i2 += blockDim.x)
        if (hist[i2]) atomicAdd(&count[i2], hist[i2]);
}

__global__ void scan_bins(const u32* __restrict__ count, u32* __restrict__ start,
                          u32* __restrict__ cursor, int nbins) {
    __shared__ u32 tmp[1024];
    int t = threadIdx.x;
    u32 v = (t < nbins) ? count[t] : 0u;
    tmp[t] = v;
    __syncthreads();
    for (int off = 1; off < 1024; off <<= 1) {
        u32 a = 0;
        if (t >= off) a = tmp[t - off];
        __syncthreads();
        tmp[t] += a;
        __syncthreads();
    }
    if (t < nbins) {
        u32 excl = tmp[t] - v;   // exclusive prefix
        start[t] = excl;
        cursor[t] = excl;
    }
}

// one block handles CHUNK4 int4 = 16384 elements; bin-sorted LDS staging so
// pair writes are coalesced runs (~21 pairs/bin/block).
__global__ void __launch_bounds__(256) bin_scatter_v2(const int4* __restrict__ idx4,
                                                      const float4* __restrict__ upd4,
                                                      u32* __restrict__ cursor,
                                                      u64* __restrict__ pairs, int n4) {
    __shared__ u32 hist[NBIN_PAD];      // chunk hist, then reused as sub-chunk hist
    __shared__ u32 basep[NBIN_PAD];
    __shared__ u32 rel[NBIN_PAD];
    __shared__ u32 sub_excl[NBIN_PAD];
    __shared__ u32 sub_pos[NBIN_PAD];
    __shared__ u32 tmp[256];
    __shared__ u64 stage[SUB4 * 4];     // 32 KB

    int t = threadIdx.x;
    int b0 = blockIdx.x * CHUNK4;

    for (int i = t; i < NBIN_PAD; i += 256) hist[i] = 0;
    __syncthreads();

    // ---- phase A: count whole chunk ----
#pragma unroll
    for (int k = 0; k < CHUNK4 / 256; ++k) {
        int p = b0 + t + 256 * k;
        if (p < n4) {
            int4 v = idx4[p];
            atomicAdd(&hist[((u32)v.x) >> 7], 1u);
            atomicAdd(&hist[((u32)v.y) >> 7], 1u);
            atomicAdd(&hist[((u32)v.z) >> 7], 1u);
            atomicAdd(&hist[((u32)v.w) >> 7], 1u);
        }
    }
    __syncthreads();
    // reserve global ranges, init running offsets
    for (int b = t; b < NBIN_PAD; b += 256) {
        u32 c = hist[b];
        basep[b] = c ? atomicAdd(&cursor[b], c) : 0u;
        rel[b] = 0u;
    }
    __syncthreads();

    // ---- phase B: per sub-chunk, bin-sort into LDS then coalesced flush ----
    for (int s = 0; s < NSUB; ++s) {
        int sbase = b0 + s * SUB4;
        int4 iv[4]; float4 uv[4];
#pragma unroll
        for (int k = 0; k < 4; ++k) {
            int p = sbase + t + 256 * k;
            if (p < n4) { iv[k] = idx4[p]; uv[k] = upd4[p]; }
        }
        // sub-chunk hist (reuse hist[])
        for (int i = t; i < NBIN_PAD; i += 256) hist[i] = 0;
        __syncthreads();
#pragma unroll
        for (int k = 0; k < 4; ++k) {
            int p = sbase + t + 256 * k;
            if (p < n4) {
                atomicAdd(&hist[((u32)iv[k].x) >> 7], 1u);
                atomicAdd(&hist[((u32)iv[k].y) >> 7], 1u);
                atomicAdd(&hist[((u32)iv[k].z) >> 7], 1u);
                atomicAdd(&hist[((u32)iv[k].w) >> 7], 1u);
            }
        }
        __syncthreads();
        // exclusive scan over bins: thread t owns bins 4t..4t+3
        u32 c0 = hist[4 * t + 0], c1 = hist[4 * t + 1];
        u32 c2 = hist[4 * t + 2], c3 = hist[4 * t + 3];
        u32 tsum = c0 + c1 + c2 + c3;
        tmp[t] = tsum;
        __syncthreads();
        for (int off = 1; off < 256; off <<= 1) {
            u32 a = (t >= off) ? tmp[t - off] : 0u;
            __syncthreads();
            tmp[t] += a;
            __syncthreads();
        }
        u32 texcl = tmp[t] - tsum;
        sub_excl[4 * t + 0] = texcl;
        sub_excl[4 * t + 1] = texcl + c0;
        sub_excl[4 * t + 2] = texcl + c0 + c1;
        sub_excl[4 * t + 3] = texcl + c0 + c1 + c2;
        sub_pos[4 * t + 0] = sub_excl[4 * t + 0];
        sub_pos[4 * t + 1] = sub_excl[4 * t + 1];
        sub_pos[4 * t + 2] = sub_excl[4 * t + 2];
        sub_pos[4 * t + 3] = sub_excl[4 * t + 3];
        __syncthreads();
        // place pairs bin-sorted into stage[]
#pragma unroll
        for (int k = 0; k < 4; ++k) {
            int p = sbase + t + 256 * k;
            if (p >= n4) continue;
            u32 colbase = ((u32)p * 4u) & 255u;
            int rows[4] = {iv[k].x, iv[k].y, iv[k].z, iv[k].w};
            float vals[4] = {uv[k].x, uv[k].y, uv[k].z, uv[k].w};
#pragma unroll
            for (int c = 0; c < 4; ++c) {
                u32 row = (u32)rows[c];
                u32 slot = atomicAdd(&sub_pos[row >> 7], 1u);
                stage[slot] = ((u64)__float_as_uint(vals[c]) << 32)
                            | ((u64)row << 8) | (u64)(colbase + (u32)c);
            }
        }
        __syncthreads();
        // coalesced flush: consecutive slots -> consecutive global addresses per bin run
        int sv = n4 - sbase; if (sv > SUB4) sv = SUB4; if (sv < 0) sv = 0;
        int scount = 4 * sv;
        for (int i = t; i < scount; i += 256) {
            u64 pr = stage[i];
            u32 rc  = (u32)pr & 0x1ffffffu;   // row<<8 | col
            u32 row = rc >> 8;
            u32 bin = row >> 7;
            u32 dest = basep[bin] + rel[bin] + ((u32)i - sub_excl[bin]);
            u32 key = ((row & 127u) << 8) | (rc & 255u);
            pairs[dest] = (pr & 0xffffffff00000000ull) | (u64)key;
        }
        __syncthreads();
        for (int b = t; b < NBIN_PAD; b += 256) rel[b] += sub_pos[b] - sub_excl[b];
        __syncthreads();
    }
}

// one block per bin: LDS-accumulate pairs, then out = self + acc (fused copy)
__global__ void __launch_bounds__(1024) apply_bins(const float4* __restrict__ self4,
                                                   const u64* __restrict__ pairs,
                                                   const u32* __restrict__ start,
                                                   const u32* __restrict__ endc,
                                                   float4* __restrict__ out4, int nrows) {
    __shared__ float acc[RB * DCOLS];   // 128 KB
    int t = threadIdx.x;
    int b = blockIdx.x;
    float4* acc4 = (float4*)acc;
    const int NACC4 = RB * DCOLS / 4;   // 8192
    for (int i = t; i < NACC4; i += 1024) acc4[i] = make_float4(0.f, 0.f, 0.f, 0.f);
    __syncthreads();

    u32 s = start[b], e = endc[b];
    for (u32 i = s + (u32)t; i < e; i += 1024u) {
        u64 pr = pairs[i];
        u32 key = (u32)pr & 0x7fffu;
        atomicAdd(&acc[key], __uint_as_float((u32)(pr >> 32)));
    }
    __syncthreads();

    int r0 = b * RB;
    int nr = nrows - r0; if (nr > RB) nr = RB;
    int tot4 = nr * (DCOLS / 4);
    long base4 = (long)r0 * (DCOLS / 4);
    for (int i = t; i < tot4; i += 1024) {
        float4 a = self4[base4 + i];
        float4 c = acc4[i];
        a.x += c.x; a.y += c.y; a.z += c.z; a.w += c.w;
        out4[base4 + i] = a;
    }
}

extern "C" void kernel_launch(void* const* d_in, const int* in_sizes, int n_in,
                              void* d_out, int out_size, void* d_ws, size_t ws_size,
                              hipStream_t stream) {
    const float* self_t = (const float*)d_in[0];   // N*D fp32
    const int*   index  = (const int*)d_in[1];     // M*D int32
    const float* upd    = (const float*)d_in[2];   // M*D fp32
    float* out = (float*)d_out;

    const int nd = out_size;      // N*D
    const int md = in_sizes[1];   // M*D
    const int nrows = nd / DCOLS;
    const int nbins = (nrows + RB - 1) / RB;

    size_t need = (size_t)PAIRS_OFF + (size_t)md * 8;
    if (ws_size < need || nbins > MAXBINS || (md & 3) || (nd & 3)) {
        copy_f4<<<2048, 256, 0, stream>>>((const float4*)self_t, (float4*)out, nd / 4);
        scatter_add4<<<4096, 256, 0, stream>>>((const int4*)index, (const float4*)upd, out, md / 4);
        return;
    }

    u32* count  = (u32*)d_ws;
    u32* start  = count + 1024;
    u32* cursor = count + 2048;
    u64* pairs  = (u64*)((char*)d_ws + PAIRS_OFF);
    int n4 = md / 4;

    zero_meta<<<1, 1024, 0, stream>>>(count, nbins);
    count_bins<<<1024, 256, 0, stream>>>((const int4*)index, count, n4);
    scan_bins<<<1, 1024, 0, stream>>>(count, start, cursor, nbins);
    int sblocks = (n4 + CHUNK4 - 1) / CHUNK4;
    bin_scatter_v2<<<sblocks, 256, 0, stream>>>((const int4*)index, (const float4*)upd,
                                                cursor, pairs, n4);
    apply_bins<<<nbins, 1024, 0, stream>>>((const float4*)self_t, pairs, start, cursor,
                                           (float4*)out, nrows);
}

// Round 4
// 229.750 us; speedup vs baseline: 2.8465x; 1.1111x over previous
//
#include <hip/hip_runtime.h>

#define DCOLS 256
#define RB 128             // rows per bin
#define NBIN_PAD 1024      // padded bin count (actual 782)
#define PAIRS_OFF 16384    // byte offset of pairs[] in d_ws
#define CHUNK4 4096        // int4 per block in scatter (16384 elements)
#define SUB4 1024          // int4 per sub-chunk (4096 elements)
#define NSUB (CHUNK4 / SUB4)

typedef unsigned int u32;
typedef unsigned short u16;
typedef unsigned long long u64;

// ---------------- fallback path ----------------
__global__ void copy_f4(const float4* __restrict__ src, float4* __restrict__ dst, int n4) {
    int i = blockIdx.x * blockDim.x + threadIdx.x;
    int stride = gridDim.x * blockDim.x;
    for (; i < n4; i += stride) dst[i] = src[i];
}

__global__ void scatter_add4(const int4* __restrict__ index,
                             const float4* __restrict__ upd,
                             float* __restrict__ out, int n4) {
    int i = blockIdx.x * blockDim.x + threadIdx.x;
    int stride = gridDim.x * blockDim.x;
    for (; i < n4; i += stride) {
        int4 idx  = index[i];
        float4 u  = upd[i];
        int j = (i << 2) & (DCOLS - 1);
        atomicAdd(&out[idx.x * DCOLS + j + 0], u.x);
        atomicAdd(&out[idx.y * DCOLS + j + 1], u.y);
        atomicAdd(&out[idx.z * DCOLS + j + 2], u.z);
        atomicAdd(&out[idx.w * DCOLS + j + 3], u.w);
    }
}

// ---------------- binned path ----------------
__global__ void zero_meta(u32* __restrict__ count, int nbins) {
    int i = threadIdx.x;
    if (i < nbins) count[i] = 0;
}

__global__ void __launch_bounds__(256) count_bins(const int4* __restrict__ idx4,
                                                  u32* __restrict__ count, int n4) {
    __shared__ u32 hist[NBIN_PAD];
    for (int i = threadIdx.x; i < NBIN_PAD; i += blockDim.x) hist[i] = 0;
    __syncthreads();
    int i = blockIdx.x * blockDim.x + threadIdx.x;
    int stride = gridDim.x * blockDim.x;
    for (; i < n4; i += stride) {
        int4 v = idx4[i];
        atomicAdd(&hist[((u32)v.x) >> 7], 1u);
        atomicAdd(&hist[((u32)v.y) >> 7], 1u);
        atomicAdd(&hist[((u32)v.z) >> 7], 1u);
        atomicAdd(&hist[((u32)v.w) >> 7], 1u);
    }
    __syncthreads();
    for (int i2 = threadIdx.x; i2 < NBIN_PAD; i2 += blockDim.x)
        if (hist[i2]) atomicAdd(&count[i2], hist[i2]);
}

__global__ void scan_bins(const u32* __restrict__ count, u32* __restrict__ start,
                          u32* __restrict__ cursor, int nbins) {
    __shared__ u32 tmp[1024];
    int t = threadIdx.x;
    u32 v = (t < nbins) ? count[t] : 0u;
    tmp[t] = v;
    __syncthreads();
    for (int off = 1; off < 1024; off <<= 1) {
        u32 a = 0;
        if (t >= off) a = tmp[t - off];
        __syncthreads();
        tmp[t] += a;
        __syncthreads();
    }
    if (t < nbins) {
        u32 excl = tmp[t] - v;
        start[t] = excl;
        cursor[t] = excl;
    }
}

// one block handles CHUNK4 int4 = 16384 elements. LDS ~42KB -> 3 blocks/CU.
// Wave-shfl scan: ~7 barriers per sub-chunk.
__global__ void __launch_bounds__(256) bin_scatter_v3(const int4* __restrict__ idx4,
                                                      const float4* __restrict__ upd4,
                                                      u32* __restrict__ cursor,
                                                      u64* __restrict__ pairs, int n4) {
    __shared__ u32 hist[NBIN_PAD];     // chunk counts, then per-sub cursor (pos)
    __shared__ u32 basep[NBIN_PAD];    // running global dest base per bin
    __shared__ u16 excl[NBIN_PAD];     // per-sub exclusive prefix
    __shared__ u32 wtot[4];
    __shared__ u64 stage[SUB4 * 4];    // 32 KB

    int t = threadIdx.x;
    int lane = t & 63, wid = t >> 6;
    int b0 = blockIdx.x * CHUNK4;

    for (int i = t; i < NBIN_PAD; i += 256) hist[i] = 0;
    __syncthreads();

    // ---- phase A: count whole chunk, reserve global ranges ----
#pragma unroll
    for (int k = 0; k < CHUNK4 / 256; ++k) {
        int p = b0 + t + 256 * k;
        if (p < n4) {
            int4 v = idx4[p];
            atomicAdd(&hist[((u32)v.x) >> 7], 1u);
            atomicAdd(&hist[((u32)v.y) >> 7], 1u);
            atomicAdd(&hist[((u32)v.z) >> 7], 1u);
            atomicAdd(&hist[((u32)v.w) >> 7], 1u);
        }
    }
    __syncthreads();
    for (int b = t; b < NBIN_PAD; b += 256) {
        u32 c = hist[b];
        basep[b] = c ? atomicAdd(&cursor[b], c) : 0u;
    }
    __syncthreads();

    // ---- phase B: per sub-chunk, bin-sort into LDS then coalesced flush ----
    for (int s = 0; s < NSUB; ++s) {
        int sbase = b0 + s * SUB4;
        int4 iv[4]; float4 uv[4];
#pragma unroll
        for (int k = 0; k < 4; ++k) {
            int p = sbase + t + 256 * k;
            if (p < n4) { iv[k] = idx4[p]; uv[k] = upd4[p]; }
        }
        // zero sub-hist
        for (int i = t; i < NBIN_PAD; i += 256) hist[i] = 0;
        __syncthreads();
        // sub-chunk histogram
#pragma unroll
        for (int k = 0; k < 4; ++k) {
            int p = sbase + t + 256 * k;
            if (p < n4) {
                atomicAdd(&hist[((u32)iv[k].x) >> 7], 1u);
                atomicAdd(&hist[((u32)iv[k].y) >> 7], 1u);
                atomicAdd(&hist[((u32)iv[k].z) >> 7], 1u);
                atomicAdd(&hist[((u32)iv[k].w) >> 7], 1u);
            }
        }
        __syncthreads();
        // wave-level exclusive scan: thread t owns bins 4t..4t+3
        u32 c0 = hist[4 * t + 0], c1 = hist[4 * t + 1];
        u32 c2 = hist[4 * t + 2], c3 = hist[4 * t + 3];
        u32 tsum = c0 + c1 + c2 + c3;
        u32 incl = tsum;
#pragma unroll
        for (int d = 1; d < 64; d <<= 1) {
            u32 y = __shfl_up(incl, (unsigned)d, 64);
            if (lane >= d) incl += y;
        }
        if (lane == 63) wtot[wid] = incl;
        __syncthreads();
        u32 woff = 0;
#pragma unroll
        for (int w = 0; w < 4; ++w) woff += (w < wid) ? wtot[w] : 0u;
        u32 base = woff + incl - tsum;
        u32 e0 = base, e1 = base + c0, e2 = e1 + c1, e3 = e2 + c2;
        excl[4 * t + 0] = (u16)e0; excl[4 * t + 1] = (u16)e1;
        excl[4 * t + 2] = (u16)e2; excl[4 * t + 3] = (u16)e3;
        hist[4 * t + 0] = e0; hist[4 * t + 1] = e1;   // hist becomes cursor
        hist[4 * t + 2] = e2; hist[4 * t + 3] = e3;
        __syncthreads();
        // stage bin-sorted
#pragma unroll
        for (int k = 0; k < 4; ++k) {
            int p = sbase + t + 256 * k;
            if (p >= n4) continue;
            int rows[4] = {iv[k].x, iv[k].y, iv[k].z, iv[k].w};
            float vals[4] = {uv[k].x, uv[k].y, uv[k].z, uv[k].w};
            u32 colbase = ((u32)p * 4u) & 255u;
#pragma unroll
            for (int c = 0; c < 4; ++c) {
                u32 row = (u32)rows[c];
                u32 slot = atomicAdd(&hist[row >> 7], 1u);
                stage[slot] = ((u64)__float_as_uint(vals[c]) << 32)
                            | ((u64)row << 8) | (u64)(colbase + (u32)c);
            }
        }
        __syncthreads();
        // coalesced flush
        int sv = n4 - sbase; if (sv > SUB4) sv = SUB4; if (sv < 0) sv = 0;
        int scount = 4 * sv;
        for (int i = t; i < scount; i += 256) {
            u64 pr = stage[i];
            u32 rc  = (u32)pr & 0x1ffffffu;   // row<<8 | col
            u32 row = rc >> 8;
            u32 bin = row >> 7;
            u32 dest = basep[bin] + ((u32)i - (u32)excl[bin]);
            u32 key = ((row & 127u) << 8) | (rc & 255u);
            pairs[dest] = (pr & 0xffffffff00000000ull) | (u64)key;
        }
        __syncthreads();
        // advance bases (hist = end cursor, excl = start)
        for (int b = t; b < NBIN_PAD; b += 256) basep[b] += hist[b] - (u32)excl[b];
        __syncthreads();
    }
}

// two blocks per bin (column halves): 64KB LDS, 1024 thr -> 2 blocks/CU
#define APPLY_P(p) { u32 k_ = (u32)(p); \
    if (((k_ >> 7) & 1u) == half) \
        atomicAdd(&acc[((k_ >> 8) & 127u) * 128u + (k_ & 127u)], \
                  __uint_as_float((u32)((p) >> 32))); }

__global__ void __launch_bounds__(1024, 8) apply_half(const float4* __restrict__ self4,
                                                      const u64* __restrict__ pairs,
                                                      const u32* __restrict__ start,
                                                      const u32* __restrict__ endc,
                                                      float4* __restrict__ out4, int nrows) {
    __shared__ float acc[RB * 128];   // 64 KB
    int t = threadIdx.x;
    int bin = blockIdx.x >> 1;
    u32 half = blockIdx.x & 1u;
    float4* acc4 = (float4*)acc;
    for (int i = t; i < RB * 32; i += 1024) acc4[i] = make_float4(0.f, 0.f, 0.f, 0.f);
    __syncthreads();

    u32 s = start[bin], e = endc[bin];
    u32 i = s + (u32)t;
    for (; i + 3072u < e; i += 4096u) {
        u64 p0 = pairs[i];
        u64 p1 = pairs[i + 1024u];
        u64 p2 = pairs[i + 2048u];
        u64 p3 = pairs[i + 3072u];
        APPLY_P(p0); APPLY_P(p1); APPLY_P(p2); APPLY_P(p3);
    }
    for (; i < e; i += 1024u) { u64 p0 = pairs[i]; APPLY_P(p0); }
    __syncthreads();

    int r0 = bin * RB;
    int nr = nrows - r0; if (nr > RB) nr = RB;
    int tot4 = nr * 32;
    for (int i2 = t; i2 < tot4; i2 += 1024) {
        int r = i2 >> 5, c4 = i2 & 31;
        long g = (long)(r0 + r) * 64 + (long)(half * 32u) + c4;
        float4 a = self4[g];
        float4 c = acc4[(r << 5) + c4];
        a.x += c.x; a.y += c.y; a.z += c.z; a.w += c.w;
        out4[g] = a;
    }
}

extern "C" void kernel_launch(void* const* d_in, const int* in_sizes, int n_in,
                              void* d_out, int out_size, void* d_ws, size_t ws_size,
                              hipStream_t stream) {
    const float* self_t = (const float*)d_in[0];   // N*D fp32
    const int*   index  = (const int*)d_in[1];     // M*D int32
    const float* upd    = (const float*)d_in[2];   // M*D fp32
    float* out = (float*)d_out;

    const int nd = out_size;      // N*D
    const int md = in_sizes[1];   // M*D
    const int nrows = nd / DCOLS;
    const int nbins = (nrows + RB - 1) / RB;

    size_t need = (size_t)PAIRS_OFF + (size_t)md * 8;
    if (ws_size < need || nbins > NBIN_PAD || (md & 3) || (nd & 3)) {
        copy_f4<<<2048, 256, 0, stream>>>((const float4*)self_t, (float4*)out, nd / 4);
        scatter_add4<<<4096, 256, 0, stream>>>((const int4*)index, (const float4*)upd, out, md / 4);
        return;
    }

    u32* count  = (u32*)d_ws;
    u32* start  = count + 1024;
    u32* cursor = count + 2048;
    u64* pairs  = (u64*)((char*)d_ws + PAIRS_OFF);
    int n4 = md / 4;

    zero_meta<<<1, 1024, 0, stream>>>(count, nbins);
    count_bins<<<1024, 256, 0, stream>>>((const int4*)index, count, n4);
    scan_bins<<<1, 1024, 0, stream>>>(count, start, cursor, nbins);
    int sblocks = (n4 + CHUNK4 - 1) / CHUNK4;
    bin_scatter_v3<<<sblocks, 256, 0, stream>>>((const int4*)index, (const float4*)upd,
                                                cursor, pairs, n4);
    apply_half<<<2 * nbins, 1024, 0, stream>>>((const float4*)self_t, pairs, start, cursor,
                                               (float4*)out, nrows);
}